// Round 4
// baseline (352.301 us; speedup 1.0000x reference)
//
#include <hip/hip_runtime.h>
#include <hip/hip_bf16.h>

// Spectral_Atten: q,k,v = dwconv3x3(conv1x1(x,W*)); channel-attention per head;
// out = conv1x1(attn@v, Wp).
// R1: split latency-bound fused dwgram -> k_dw + k_gram (554->398us).
// R2: k_mmat 160us @0.37% occupancy -> 48-block LDS-tiled (398->281us).
// R3: k_conv1 was 121us, issue-bound (scalar transposed LDS staging w/ 6.3M
// bank conflicts + 48 scalar 2B stores/thread, 20% occupancy). Replaced with
// k_xT (x -> x^T, no LDS, coalesced) + k_conv1t (both MFMA operands direct
// from global, zero LDS/barriers, ushort4 vector stores).

using bf16x8 = __attribute__((ext_vector_type(8))) short;
using f32x4  = __attribute__((ext_vector_type(4))) float;
using fvec4  = __attribute__((ext_vector_type(4))) float;
using u16x4  = __attribute__((ext_vector_type(4))) unsigned short;

#define NB     8
#define CDIM   192
#define NHEADS 6
#define IMGW   128
#define NPIX   16384

__device__ __forceinline__ float b2f(unsigned short u){
  return __uint_as_float(((unsigned int)u) << 16);
}
__device__ __forceinline__ unsigned short f2b(float f){
  unsigned int x = __float_as_uint(f);
  return (unsigned short)((x + 0x7FFFu + ((x >> 16) & 1u)) >> 16);
}
__device__ __forceinline__ float ldT(const void* p, size_t i, int isbf){
  return isbf ? b2f(((const unsigned short*)p)[i]) : ((const float*)p)[i];
}
__device__ __forceinline__ f32x4 MF(bf16x8 a, bf16x8 b, f32x4 c){
  return __builtin_amdgcn_mfma_f32_16x16x32_bf16(a, b, c, 0, 0, 0);
}

// ---- dtype detector (bf16 vs fp32 device buffers)
__global__ void k_detect(const unsigned short* x, int* flag){
  int l = threadIdx.x;
  int cnt = 0;
#pragma unroll
  for (int i = 0; i < 2; ++i){
    unsigned short u = x[(l*2 + i)*2];
    float a = fabsf(b2f(u));
    if (a == 0.f || (a > 1e-4f && a < 20.f)) ++cnt;
  }
  int tot = __popcll(__ballot(cnt >= 1)) + __popcll(__ballot(cnt >= 2));
  if (l == 0) *flag = (tot > 64) ? 1 : 0;
}

// ---- pack Wq,Wk,Wv into stacked bf16 [576][192]
__global__ __launch_bounds__(256) void k_prep(const void* Wq, const void* Wk, const void* Wv,
    unsigned short* Wqkv, const int* flag){
  int i = blockIdx.x*256 + threadIdx.x;
  if (i >= 576*192) return;
  int isbf = *flag;
  int m = i / 192, kk = i % 192;
  int t = m / 192;
  const void* W = (t == 0) ? Wq : (t == 1) ? Wk : Wv;
  Wqkv[i] = f2b(ldT(W, (size_t)(m % 192)*192 + kk, isbf));
}

// ---- x[b][c][n] -> xT[b][n][c] (bf16). No LDS. Each thread owns 2 full rows
// of xT (n, n+1): reads are wave-coalesced (lanes = consecutive n-pairs), and
// the thread covers its 2x384B output rows entirely -> L2 merges the 16B
// chunk stores into full lines.
__global__ __launch_bounds__(256) void k_xT(const void* x, unsigned short* xT, const int* flag){
  int np = blockIdx.x*256 + threadIdx.x;   // n-pair index, 0..8191
  int b = blockIdx.y;
  int n = np*2;
  int isbf = *flag;
  unsigned short* dst = xT + ((size_t)b*NPIX + n)*CDIM;
#pragma unroll 1
  for (int cg = 0; cg < 24; ++cg){
    bf16x8 a0, a1;
    if (isbf){
      const unsigned short* xs = (const unsigned short*)x + (size_t)b*CDIM*NPIX;
#pragma unroll
      for (int i = 0; i < 8; ++i){
        unsigned int u = *(const unsigned int*)(xs + (size_t)(cg*8+i)*NPIX + n);
        a0[i] = (short)(u & 0xffffu);
        a1[i] = (short)(u >> 16);
      }
    } else {
      const float* xf = (const float*)x + (size_t)b*CDIM*NPIX;
#pragma unroll
      for (int i = 0; i < 8; ++i){
        fvec4 dummy;
        float f0 = xf[(size_t)(cg*8+i)*NPIX + n];
        float f1 = xf[(size_t)(cg*8+i)*NPIX + n + 1];
        a0[i] = (short)f2b(f0);
        a1[i] = (short)f2b(f1);
        (void)dummy;
      }
    }
    *(bf16x8*)(dst + cg*8)        = a0;
    *(bf16x8*)(dst + CDIM + cg*8) = a1;
  }
}

// ---- fused triple 1x1 conv from xT: zero LDS, zero barriers.
// A-operand = xT (n-side, preloaded 12 frags reused 36x), B-operand = Wqkv
// rows (k-contiguous from L1/L2). D[row=n(lk*4+r)][col=m(lr)] -> each lane
// holds 4 consecutive pixels for one m: ushort4 8B vector stores.
__global__ __launch_bounds__(256) void k_conv1t(const unsigned short* xT,
    const unsigned short* Wqkv, unsigned short* q0, unsigned short* k0,
    unsigned short* v0){
  int tid = threadIdx.x;
  int nbk = blockIdx.x, b = blockIdx.y;
  int w = tid >> 6, l = tid & 63, lr = l & 15, lk = l >> 4;
  int n0 = nbk*128 + w*32;
  const unsigned short* xrow = xT + ((size_t)b*NPIX + n0)*CDIM;
  bf16x8 afr[2][6];
#pragma unroll
  for (int nf = 0; nf < 2; ++nf)
#pragma unroll
    for (int kc = 0; kc < 6; ++kc)
      afr[nf][kc] = *(const bf16x8*)(xrow + (size_t)(nf*16 + lr)*CDIM + kc*32 + lk*8);
#pragma unroll 1
  for (int mt = 0; mt < 36; ++mt){
    f32x4 acc0 = {}, acc1 = {};
#pragma unroll
    for (int kc = 0; kc < 6; ++kc){
      bf16x8 bfv = *(const bf16x8*)(Wqkv + (size_t)(mt*16 + lr)*CDIM + kc*32 + lk*8);
      acc0 = MF(afr[0][kc], bfv, acc0);
      acc1 = MF(afr[1][kc], bfv, acc1);
    }
    int t = mt / 12;                        // uniform per mt (12*16 = 192)
    int mloc = (mt - t*12)*16 + lr;         // per-lane output channel
    unsigned short* dst = ((t == 0) ? q0 : (t == 1) ? k0 : v0)
                        + (size_t)(b*CDIM + mloc)*NPIX + n0 + lk*4;
    u16x4 p0, p1;
#pragma unroll
    for (int r = 0; r < 4; ++r){ p0[r] = f2b(acc0[r]); p1[r] = f2b(acc1[r]); }
    *(u16x4*)(dst)      = p0;
    *(u16x4*)(dst + 16) = p1;
  }
}

// ---- depthwise 3x3, in-place on q0/k0/v0; per-(b,t,c) sum-of-squares for q,k.
__global__ __launch_bounds__(256) void k_dw(unsigned short* q0, unsigned short* k0,
    unsigned short* v0, const void* wqd, const void* wkd, const void* wvd,
    float* Nsq, const int* flag){
  __shared__ unsigned short img[128][136];
  __shared__ float wred[4];
  int tid = threadIdx.x;
  int t = blockIdx.x, c = blockIdx.y, b = blockIdx.z;
  int isbf = *flag;
  unsigned short* base = ((t == 0) ? q0 : (t == 1) ? k0 : v0) + (size_t)(b*CDIM + c)*NPIX;
  const void* wd = (t == 0) ? wqd : (t == 1) ? wkd : wvd;
  float w9[9];
#pragma unroll
  for (int e = 0; e < 9; ++e) w9[e] = ldT(wd, (size_t)c*9 + e, isbf);
  for (int r = tid; r < 2048; r += 256){
    int row = r >> 4, col8 = (r & 15)*8;
    *(bf16x8*)(&img[row][col8]) = *(const bf16x8*)(base + row*IMGW + col8);
  }
  __syncthreads();
  int tr = tid >> 2, tc = tid & 3;
  int c0 = tc * 32, r0 = tr * 2;
  const bf16x8 zv = {0,0,0,0,0,0,0,0};
  int  rowi[4]; bool valid[4];
  bf16x8 cur[4], nxt[4];
  float carry[4];
#pragma unroll
  for (int d = 0; d < 4; ++d){
    rowi[d] = r0 - 1 + d;
    valid[d] = (rowi[d] >= 0) && (rowi[d] < 128);
    cur[d] = valid[d] ? *(const bf16x8*)(&img[rowi[d]][c0]) : zv;
    carry[d] = (valid[d] && c0 > 0) ? b2f(img[rowi[d]][c0 - 1]) : 0.f;
  }
  float sq = 0.f;
#pragma unroll
  for (int j = 0; j < 4; ++j){
    float right0[4];
    if (j < 3){
#pragma unroll
      for (int d = 0; d < 4; ++d){
        nxt[d] = valid[d] ? *(const bf16x8*)(&img[rowi[d]][c0 + 8*(j+1)]) : zv;
        right0[d] = b2f((unsigned short)nxt[d][0]);
      }
    } else {
#pragma unroll
      for (int d = 0; d < 4; ++d)
        right0[d] = (valid[d] && (c0 + 32 < 128)) ? b2f(img[rowi[d]][c0 + 32]) : 0.f;
    }
    float f[4][8];
#pragma unroll
    for (int d = 0; d < 4; ++d)
#pragma unroll
      for (int i = 0; i < 8; ++i) f[d][i] = b2f((unsigned short)cur[d][i]);
#pragma unroll
    for (int rr = 0; rr < 2; ++rr){
      float o[8];
#pragma unroll
      for (int cc = 0; cc < 8; ++cc){
        float a = 0.f;
#pragma unroll
        for (int d2 = 0; d2 < 3; ++d2){
          int d = rr + d2;
          float lf = (cc == 0) ? carry[d] : f[d][cc-1];
          float md = f[d][cc];
          float rt = (cc == 7) ? right0[d] : f[d][cc+1];
          a = fmaf(w9[d2*3+0], lf, a);
          a = fmaf(w9[d2*3+1], md, a);
          a = fmaf(w9[d2*3+2], rt, a);
        }
        o[cc] = a;
        if (t < 2) sq = fmaf(a, a, sq);
      }
      bf16x8 ov;
#pragma unroll
      for (int cc = 0; cc < 8; ++cc) ov[cc] = (short)f2b(o[cc]);
      *(bf16x8*)(base + (r0 + rr)*IMGW + c0 + 8*j) = ov;
    }
#pragma unroll
    for (int d = 0; d < 4; ++d) carry[d] = f[d][7];
    if (j < 3){
#pragma unroll
      for (int d = 0; d < 4; ++d) cur[d] = nxt[d];
    }
  }
  if (t < 2){
#pragma unroll
    for (int off = 32; off > 0; off >>= 1) sq += __shfl_xor(sq, off);
    if ((tid & 63) == 0) wred[tid >> 6] = sq;
    __syncthreads();
    if (tid == 0) Nsq[((size_t)b*2 + t)*CDIM + c] = wred[0] + wred[1] + wred[2] + wred[3];
  }
}

// ---- gram partials: S over px chunk of 2048, MFMA fragments from global
__global__ __launch_bounds__(256) void k_gram(const unsigned short* qd,
    const unsigned short* kd, float* Spart){
  __shared__ float S_lds[1024];
  int tid = threadIdx.x;
  int cs = blockIdx.x, h = blockIdx.y, b = blockIdx.z;
  int w = tid >> 6, l = tid & 63, lr = l & 15, lk = l >> 4;
  for (int e = tid; e < 1024; e += 256) S_lds[e] = 0.f;
  __syncthreads();
  const unsigned short* qb = qd + (size_t)(b*CDIM + h*32)*NPIX;
  const unsigned short* kb = kd + (size_t)(b*CDIM + h*32)*NPIX;
  f32x4 g4[2][2] = {};
  int pxb = cs*2048 + w*512 + lk*8;
#pragma unroll
  for (int kc = 0; kc < 16; ++kc){
    int px = pxb + kc*32;
    bf16x8 a0 = *(const bf16x8*)(qb + (size_t)lr*NPIX + px);
    bf16x8 a1 = *(const bf16x8*)(qb + (size_t)(16+lr)*NPIX + px);
    bf16x8 b0 = *(const bf16x8*)(kb + (size_t)lr*NPIX + px);
    bf16x8 b1 = *(const bf16x8*)(kb + (size_t)(16+lr)*NPIX + px);
    g4[0][0] = MF(a0, b0, g4[0][0]);
    g4[0][1] = MF(a0, b1, g4[0][1]);
    g4[1][0] = MF(a1, b0, g4[1][0]);
    g4[1][1] = MF(a1, b1, g4[1][1]);
  }
  for (int wv = 0; wv < 4; ++wv){
    if (w == wv){
#pragma unroll
      for (int mi = 0; mi < 2; ++mi)
#pragma unroll
        for (int ni = 0; ni < 2; ++ni)
#pragma unroll
          for (int r = 0; r < 4; ++r)
            S_lds[(mi*16 + lk*4 + r)*32 + ni*16 + lr] += g4[mi][ni][r];
    }
    __syncthreads();
  }
  int bidx = (b*NHEADS + h)*8 + cs;
  for (int e = tid; e < 1024; e += 256) Spart[(size_t)bidx*1024 + e] = S_lds[e];
}

// ---- reduce partials, l2norm scaling + rescale, softmax rows
__global__ __launch_bounds__(256) void k_attn(const float* Spart, const float* Nsq,
    const void* rescale, float* attnG, const int* flag){
  __shared__ float S[1024];
  __shared__ float rn[64];
  int bh = blockIdx.x, tid = threadIdx.x;
  int b = bh / NHEADS, h = bh % NHEADS;
  int isbf = *flag;
  for (int e = tid; e < 1024; e += 256){
    float a = 0.f;
    for (int st = 0; st < 8; ++st) a += Spart[((size_t)bh*8 + st)*1024 + e];
    S[e] = a;
  }
  if (tid < 64){
    int t = tid >> 5, ch = h*32 + (tid & 31);
    float a = Nsq[((size_t)b*2 + t)*CDIM + ch];
    rn[tid] = 1.f / fmaxf(sqrtf(a), 1e-12f);
  }
  __syncthreads();
  if (tid < 32){
    float sc = ldT(rescale, h, isbf);
    float lo[32], mx = -1e30f;
#pragma unroll
    for (int d = 0; d < 32; ++d){
      lo[d] = S[tid*32 + d] * rn[tid] * rn[32 + d] * sc;
      mx = fmaxf(mx, lo[d]);
    }
    float sum = 0.f;
#pragma unroll
    for (int d = 0; d < 32; ++d){ lo[d] = __expf(lo[d] - mx); sum += lo[d]; }
    float inv = 1.f / sum;
#pragma unroll
    for (int d = 0; d < 32; ++d) attnG[(size_t)bh*1024 + tid*32 + d] = lo[d] * inv;
  }
}

// ---- M[b] = Wp @ blockdiag(attn[b])  -- 48 blocks, LDS-staged operands.
__global__ __launch_bounds__(256) void k_mmat(const void* Wp, const float* attnG,
    unsigned short* Mb, const int* flag){
  __shared__ float at[NHEADS*1024];
  __shared__ float wp[32][200];
  int b = blockIdx.x, og = blockIdx.y, tid = threadIdx.x;
  int isbf = *flag;
  for (int e = tid; e < NHEADS*1024; e += 256) at[e] = attnG[(size_t)b*NHEADS*1024 + e];
  for (int e = tid; e < 32*192; e += 256){
    int r = e / 192, cdx = e % 192;
    wp[r][cdx] = ldT(Wp, (size_t)(og*32 + r)*CDIM + cdx, isbf);
  }
  __syncthreads();
  int r = tid >> 3, cg = tid & 7;
#pragma unroll 1
  for (int i = 0; i < 24; ++i){
    int dg = cg*24 + i;
    int hh = dg >> 5, d = dg & 31;
    float a = 0.f;
#pragma unroll
    for (int cc = 0; cc < 32; ++cc)
      a += wp[r][hh*32 + cc] * at[hh*1024 + cc*32 + d];
    Mb[(size_t)b*CDIM*CDIM + (size_t)(og*32 + r)*CDIM + dg] = f2b(a);
  }
}

// ---- final: out[b] = M[b] @ v[b]
__global__ __launch_bounds__(256) void k_out(const unsigned short* v, const unsigned short* Mb,
    void* out, const int* flag){
  __shared__ unsigned short Bt[64][200];
  int tid = threadIdx.x;
  int nt = blockIdx.x, b = blockIdx.y;
  int n0 = nt * 64;
  for (int r = tid; r < 1536; r += 256){
    int k = r >> 3, j8 = (r & 7) * 8;
    bf16x8 vv = *(const bf16x8*)(v + (size_t)(b*CDIM + k)*NPIX + n0 + j8);
#pragma unroll
    for (int i = 0; i < 8; ++i) Bt[j8+i][k] = (unsigned short)vv[i];
  }
  __syncthreads();
  int w = tid >> 6, l = tid & 63, lr = l & 15, lk = l >> 4;
  const unsigned short* A = Mb + (size_t)b*CDIM*CDIM;
  f32x4 acc[3][4] = {};
  for (int kc = 0; kc < 6; ++kc){
    bf16x8 af[3];
#pragma unroll
    for (int g = 0; g < 3; ++g)
      af[g] = *(const bf16x8*)(A + (size_t)(g*64 + w*16 + lr)*CDIM + kc*32 + lk*8);
#pragma unroll
    for (int nf = 0; nf < 4; ++nf){
      bf16x8 bfv = *(const bf16x8*)(&Bt[nf*16 + lr][kc*32 + lk*8]);
#pragma unroll
      for (int g = 0; g < 3; ++g) acc[g][nf] = MF(af[g], bfv, acc[g][nf]);
    }
  }
  int isbf = *flag;
#pragma unroll
  for (int g = 0; g < 3; ++g)
#pragma unroll
    for (int nf = 0; nf < 4; ++nf)
#pragma unroll
      for (int r = 0; r < 4; ++r){
        int m = g*64 + w*16 + lk*4 + r;
        size_t oi = (size_t)(b*CDIM + m)*NPIX + n0 + nf*16 + lr;
        if (isbf) ((unsigned short*)out)[oi] = f2b(acc[g][nf][r]);
        else      ((float*)out)[oi] = acc[g][nf][r];
      }
}

extern "C" void kernel_launch(void* const* d_in, const int* in_sizes, int n_in,
                              void* d_out, int out_size, void* d_ws, size_t ws_size,
                              hipStream_t stream){
  const void* x   = d_in[0];
  const void* Wq  = d_in[1];
  const void* Wk  = d_in[2];
  const void* Wv  = d_in[3];
  const void* Wqd = d_in[4];
  const void* Wkd = d_in[5];
  const void* Wvd = d_in[6];
  const void* rsc = d_in[7];
  const void* Wp  = d_in[8];

  char* ws = (char*)d_ws;
  size_t o = 0;
  int* flag             = (int*)(ws + o);            o += 256;
  unsigned short* Wqkv  = (unsigned short*)(ws + o); o += (size_t)576*192*2;
  unsigned short* q0    = (unsigned short*)(ws + o); o += (size_t)NB*CDIM*NPIX*2;
  unsigned short* k0    = (unsigned short*)(ws + o); o += (size_t)NB*CDIM*NPIX*2;
  unsigned short* v0    = (unsigned short*)(ws + o); o += (size_t)NB*CDIM*NPIX*2;
  unsigned short* xT    = (unsigned short*)(ws + o); o += (size_t)NB*NPIX*CDIM*2;
  float* Spart          = (float*)(ws + o);          o += (size_t)384*1024*4;
  float* Nsq            = (float*)(ws + o);          o += (size_t)NB*2*CDIM*4;
  float* attnG          = (float*)(ws + o);          o += (size_t)48*1024*4;
  unsigned short* Mb    = (unsigned short*)(ws + o); o += (size_t)NB*CDIM*CDIM*2;

  k_detect<<<dim3(1), 64, 0, stream>>>((const unsigned short*)x, flag);
  k_prep  <<<dim3(432), 256, 0, stream>>>(Wq, Wk, Wv, Wqkv, flag);
  k_xT    <<<dim3(32, NB), 256, 0, stream>>>(x, xT, flag);
  k_conv1t<<<dim3(128, NB), 256, 0, stream>>>(xT, Wqkv, q0, k0, v0);
  k_dw    <<<dim3(3, CDIM, NB), 256, 0, stream>>>(q0, k0, v0, Wqd, Wkd, Wvd, Nsq, flag);
  k_gram  <<<dim3(8, NHEADS, NB), 256, 0, stream>>>(q0, k0, Spart);
  k_attn  <<<dim3(48), 256, 0, stream>>>(Spart, Nsq, rsc, attnG, flag);
  k_mmat  <<<dim3(NB, 6), 256, 0, stream>>>(Wp, attnG, Mb, flag);
  k_out   <<<dim3(256, 8), 256, 0, stream>>>(v0, Mb, d_out, flag);
}

// Round 5
// 260.326 us; speedup vs baseline: 1.3533x; 1.3533x over previous
//
#include <hip/hip_runtime.h>
#include <hip/hip_bf16.h>

// Spectral_Atten: q,k,v = dwconv3x3(conv1x1(x,W*)); channel-attention per head;
// out = conv1x1(attn@v, Wp).
// R1: split latency-bound fused dwgram -> k_dw + k_gram (554->398us).
// R2: k_mmat 160us @0.37% occupancy -> 48-block LDS-tiled (398->281us).
// R3: FAILED. xT+conv1t (no LDS, vector stores) left conv1 at 122us and added
//     70us of transpose. Diagnosis: all variants store 32B (or 16B) segments;
//     measured hbm_gbps ~1.24TB/s during stores == whole-kernel duration.
// R4: every epilogue goes through LDS -> wave-contiguous 1KB bf16x8 stores.
//     conv1 restored to R2 structure + LDS epilogue; k_dw and k_out likewise.

using bf16x8 = __attribute__((ext_vector_type(8))) short;
using f32x4  = __attribute__((ext_vector_type(4))) float;
using fvec4  = __attribute__((ext_vector_type(4))) float;

#define NB     8
#define CDIM   192
#define NHEADS 6
#define IMGW   128
#define NPIX   16384

__device__ __forceinline__ float b2f(unsigned short u){
  return __uint_as_float(((unsigned int)u) << 16);
}
__device__ __forceinline__ unsigned short f2b(float f){
  unsigned int x = __float_as_uint(f);
  return (unsigned short)((x + 0x7FFFu + ((x >> 16) & 1u)) >> 16);
}
__device__ __forceinline__ float ldT(const void* p, size_t i, int isbf){
  return isbf ? b2f(((const unsigned short*)p)[i]) : ((const float*)p)[i];
}
__device__ __forceinline__ f32x4 MF(bf16x8 a, bf16x8 b, f32x4 c){
  return __builtin_amdgcn_mfma_f32_16x16x32_bf16(a, b, c, 0, 0, 0);
}

// ---- dtype detector (bf16 vs fp32 device buffers)
__global__ void k_detect(const unsigned short* x, int* flag){
  int l = threadIdx.x;
  int cnt = 0;
#pragma unroll
  for (int i = 0; i < 2; ++i){
    unsigned short u = x[(l*2 + i)*2];
    float a = fabsf(b2f(u));
    if (a == 0.f || (a > 1e-4f && a < 20.f)) ++cnt;
  }
  int tot = __popcll(__ballot(cnt >= 1)) + __popcll(__ballot(cnt >= 2));
  if (l == 0) *flag = (tot > 64) ? 1 : 0;
}

// ---- pack Wq,Wk,Wv into stacked bf16 [576][192]
__global__ __launch_bounds__(256) void k_prep(const void* Wq, const void* Wk, const void* Wv,
    unsigned short* Wqkv, const int* flag){
  int i = blockIdx.x*256 + threadIdx.x;
  if (i >= 576*192) return;
  int isbf = *flag;
  int m = i / 192, kk = i % 192;
  int t = m / 192;
  const void* W = (t == 0) ? Wq : (t == 1) ? Wk : Wv;
  Wqkv[i] = f2b(ldT(W, (size_t)(m % 192)*192 + kk, isbf));
}

// ---- fused triple 1x1 conv: q0,k0,v0 (bf16) = W{q,k,v} @ x[b].
// R4: epilogue routed through outb LDS -> contiguous 1KB wave stores.
__global__ __launch_bounds__(256) void k_conv1(const void* x, const unsigned short* Wqkv,
    unsigned short* q0, unsigned short* k0, unsigned short* v0, const int* flag){
  __shared__ unsigned short Bt[64][200];     // x-tile, transposed [px][k]
  __shared__ unsigned short outb[192][72];   // epilogue tile [m][px], 16B rows
  int tid = threadIdx.x;
  int nt = blockIdx.x, b = blockIdx.y;
  int n0 = nt * 64;
  int isbf = *flag;
  if (isbf){
    const unsigned short* xs = (const unsigned short*)x;
    for (int r = tid; r < 1536; r += 256){
      int k = r >> 3, j8 = (r & 7) * 8;
      bf16x8 v = *(const bf16x8*)(xs + (size_t)(b*CDIM + k)*NPIX + n0 + j8);
#pragma unroll
      for (int i = 0; i < 8; ++i) Bt[j8+i][k] = (unsigned short)v[i];
    }
  } else {
    const float* xf = (const float*)x;
    for (int r = tid; r < 3072; r += 256){
      int k = r >> 4, j4 = (r & 15) * 4;
      fvec4 v = *(const fvec4*)(xf + (size_t)(b*CDIM + k)*NPIX + n0 + j4);
#pragma unroll
      for (int i = 0; i < 4; ++i) Bt[j4+i][k] = f2b(v[i]);
    }
  }
  __syncthreads();
  int w = tid >> 6, l = tid & 63, lr = l & 15, lk = l >> 4;
#pragma unroll 1
  for (int t = 0; t < 3; ++t){
    f32x4 acc[3][4] = {};
    for (int kc = 0; kc < 6; ++kc){
      bf16x8 af[3];
#pragma unroll
      for (int g = 0; g < 3; ++g)
        af[g] = *(const bf16x8*)(Wqkv + ((size_t)t*CDIM + g*64 + w*16 + lr)*CDIM + kc*32 + lk*8);
#pragma unroll
      for (int nf = 0; nf < 4; ++nf){
        bf16x8 bfv = *(const bf16x8*)(&Bt[nf*16 + lr][kc*32 + lk*8]);
#pragma unroll
        for (int g = 0; g < 3; ++g) acc[g][nf] = MF(af[g], bfv, acc[g][nf]);
      }
    }
    __syncthreads();   // prev t's cooperative store done; outb free
#pragma unroll
    for (int g = 0; g < 3; ++g)
#pragma unroll
      for (int nf = 0; nf < 4; ++nf)
#pragma unroll
        for (int r = 0; r < 4; ++r)
          outb[g*64 + w*16 + lk*4 + r][nf*16 + lr] = f2b(acc[g][nf][r]);
    __syncthreads();
    unsigned short* dst = ((t == 0) ? q0 : (t == 1) ? k0 : v0) + (size_t)b*CDIM*NPIX;
    for (int e = tid; e < 1536; e += 256){
      int m = e >> 3, p8 = (e & 7) * 8;
      *(bf16x8*)(dst + (size_t)m*NPIX + n0 + p8) = *(const bf16x8*)(&outb[m][p8]);
    }
  }
}

// ---- depthwise 3x3, in-place on q0/k0/v0; per-(b,t,c) sum-of-squares for q,k.
// R4: outputs staged in outb LDS -> contiguous 1KB wave stores.
__global__ __launch_bounds__(256) void k_dw(unsigned short* q0, unsigned short* k0,
    unsigned short* v0, const void* wqd, const void* wkd, const void* wvd,
    float* Nsq, const int* flag){
  __shared__ unsigned short img[128][136];
  __shared__ unsigned short outb[128][136];
  __shared__ float wred[4];
  int tid = threadIdx.x;
  int t = blockIdx.x, c = blockIdx.y, b = blockIdx.z;
  int isbf = *flag;
  unsigned short* base = ((t == 0) ? q0 : (t == 1) ? k0 : v0) + (size_t)(b*CDIM + c)*NPIX;
  const void* wd = (t == 0) ? wqd : (t == 1) ? wkd : wvd;
  float w9[9];
#pragma unroll
  for (int e = 0; e < 9; ++e) w9[e] = ldT(wd, (size_t)c*9 + e, isbf);
  for (int r = tid; r < 2048; r += 256){
    int row = r >> 4, col8 = (r & 15)*8;
    *(bf16x8*)(&img[row][col8]) = *(const bf16x8*)(base + row*IMGW + col8);
  }
  __syncthreads();
  int tr = tid >> 2, tc = tid & 3;
  int c0 = tc * 32, r0 = tr * 2;
  const bf16x8 zv = {0,0,0,0,0,0,0,0};
  int  rowi[4]; bool valid[4];
  bf16x8 cur[4], nxt[4];
  float carry[4];
#pragma unroll
  for (int d = 0; d < 4; ++d){
    rowi[d] = r0 - 1 + d;
    valid[d] = (rowi[d] >= 0) && (rowi[d] < 128);
    cur[d] = valid[d] ? *(const bf16x8*)(&img[rowi[d]][c0]) : zv;
    carry[d] = (valid[d] && c0 > 0) ? b2f(img[rowi[d]][c0 - 1]) : 0.f;
  }
  float sq = 0.f;
#pragma unroll
  for (int j = 0; j < 4; ++j){
    float right0[4];
    if (j < 3){
#pragma unroll
      for (int d = 0; d < 4; ++d){
        nxt[d] = valid[d] ? *(const bf16x8*)(&img[rowi[d]][c0 + 8*(j+1)]) : zv;
        right0[d] = b2f((unsigned short)nxt[d][0]);
      }
    } else {
#pragma unroll
      for (int d = 0; d < 4; ++d)
        right0[d] = (valid[d] && (c0 + 32 < 128)) ? b2f(img[rowi[d]][c0 + 32]) : 0.f;
    }
    float f[4][8];
#pragma unroll
    for (int d = 0; d < 4; ++d)
#pragma unroll
      for (int i = 0; i < 8; ++i) f[d][i] = b2f((unsigned short)cur[d][i]);
#pragma unroll
    for (int rr = 0; rr < 2; ++rr){
      float o[8];
#pragma unroll
      for (int cc = 0; cc < 8; ++cc){
        float a = 0.f;
#pragma unroll
        for (int d2 = 0; d2 < 3; ++d2){
          int d = rr + d2;
          float lf = (cc == 0) ? carry[d] : f[d][cc-1];
          float md = f[d][cc];
          float rt = (cc == 7) ? right0[d] : f[d][cc+1];
          a = fmaf(w9[d2*3+0], lf, a);
          a = fmaf(w9[d2*3+1], md, a);
          a = fmaf(w9[d2*3+2], rt, a);
        }
        o[cc] = a;
        if (t < 2) sq = fmaf(a, a, sq);
      }
      bf16x8 ov;
#pragma unroll
      for (int cc = 0; cc < 8; ++cc) ov[cc] = (short)f2b(o[cc]);
      *(bf16x8*)(&outb[r0 + rr][c0 + 8*j]) = ov;
    }
#pragma unroll
    for (int d = 0; d < 4; ++d) carry[d] = f[d][7];
    if (j < 3){
#pragma unroll
      for (int d = 0; d < 4; ++d) cur[d] = nxt[d];
    }
  }
  if (t < 2){
#pragma unroll
    for (int off = 32; off > 0; off >>= 1) sq += __shfl_xor(sq, off);
    if ((tid & 63) == 0) wred[tid >> 6] = sq;
  }
  __syncthreads();
  for (int e = tid; e < 2048; e += 256){
    int row = e >> 4, p8 = (e & 15) * 8;
    *(bf16x8*)(base + row*IMGW + p8) = *(const bf16x8*)(&outb[row][p8]);
  }
  if (t < 2 && tid == 0)
    Nsq[((size_t)b*2 + t)*CDIM + c] = wred[0] + wred[1] + wred[2] + wred[3];
}

// ---- gram partials: S over px chunk of 2048, MFMA fragments from global
__global__ __launch_bounds__(256) void k_gram(const unsigned short* qd,
    const unsigned short* kd, float* Spart){
  __shared__ float S_lds[1024];
  int tid = threadIdx.x;
  int cs = blockIdx.x, h = blockIdx.y, b = blockIdx.z;
  int w = tid >> 6, l = tid & 63, lr = l & 15, lk = l >> 4;
  for (int e = tid; e < 1024; e += 256) S_lds[e] = 0.f;
  __syncthreads();
  const unsigned short* qb = qd + (size_t)(b*CDIM + h*32)*NPIX;
  const unsigned short* kb = kd + (size_t)(b*CDIM + h*32)*NPIX;
  f32x4 g4[2][2] = {};
  int pxb = cs*2048 + w*512 + lk*8;
#pragma unroll
  for (int kc = 0; kc < 16; ++kc){
    int px = pxb + kc*32;
    bf16x8 a0 = *(const bf16x8*)(qb + (size_t)lr*NPIX + px);
    bf16x8 a1 = *(const bf16x8*)(qb + (size_t)(16+lr)*NPIX + px);
    bf16x8 b0 = *(const bf16x8*)(kb + (size_t)lr*NPIX + px);
    bf16x8 b1 = *(const bf16x8*)(kb + (size_t)(16+lr)*NPIX + px);
    g4[0][0] = MF(a0, b0, g4[0][0]);
    g4[0][1] = MF(a0, b1, g4[0][1]);
    g4[1][0] = MF(a1, b0, g4[1][0]);
    g4[1][1] = MF(a1, b1, g4[1][1]);
  }
  for (int wv = 0; wv < 4; ++wv){
    if (w == wv){
#pragma unroll
      for (int mi = 0; mi < 2; ++mi)
#pragma unroll
        for (int ni = 0; ni < 2; ++ni)
#pragma unroll
          for (int r = 0; r < 4; ++r)
            S_lds[(mi*16 + lk*4 + r)*32 + ni*16 + lr] += g4[mi][ni][r];
    }
    __syncthreads();
  }
  int bidx = (b*NHEADS + h)*8 + cs;
  for (int e = tid; e < 1024; e += 256) Spart[(size_t)bidx*1024 + e] = S_lds[e];
}

// ---- reduce partials, l2norm scaling + rescale, softmax rows
__global__ __launch_bounds__(256) void k_attn(const float* Spart, const float* Nsq,
    const void* rescale, float* attnG, const int* flag){
  __shared__ float S[1024];
  __shared__ float rn[64];
  int bh = blockIdx.x, tid = threadIdx.x;
  int b = bh / NHEADS, h = bh % NHEADS;
  int isbf = *flag;
  for (int e = tid; e < 1024; e += 256){
    float a = 0.f;
    for (int st = 0; st < 8; ++st) a += Spart[((size_t)bh*8 + st)*1024 + e];
    S[e] = a;
  }
  if (tid < 64){
    int t = tid >> 5, ch = h*32 + (tid & 31);
    float a = Nsq[((size_t)b*2 + t)*CDIM + ch];
    rn[tid] = 1.f / fmaxf(sqrtf(a), 1e-12f);
  }
  __syncthreads();
  if (tid < 32){
    float sc = ldT(rescale, h, isbf);
    float lo[32], mx = -1e30f;
#pragma unroll
    for (int d = 0; d < 32; ++d){
      lo[d] = S[tid*32 + d] * rn[tid] * rn[32 + d] * sc;
      mx = fmaxf(mx, lo[d]);
    }
    float sum = 0.f;
#pragma unroll
    for (int d = 0; d < 32; ++d){ lo[d] = __expf(lo[d] - mx); sum += lo[d]; }
    float inv = 1.f / sum;
#pragma unroll
    for (int d = 0; d < 32; ++d) attnG[(size_t)bh*1024 + tid*32 + d] = lo[d] * inv;
  }
}

// ---- M[b] = Wp @ blockdiag(attn[b])  -- 48 blocks, LDS-staged operands.
__global__ __launch_bounds__(256) void k_mmat(const void* Wp, const float* attnG,
    unsigned short* Mb, const int* flag){
  __shared__ float at[NHEADS*1024];
  __shared__ float wp[32][200];
  int b = blockIdx.x, og = blockIdx.y, tid = threadIdx.x;
  int isbf = *flag;
  for (int e = tid; e < NHEADS*1024; e += 256) at[e] = attnG[(size_t)b*NHEADS*1024 + e];
  for (int e = tid; e < 32*192; e += 256){
    int r = e / 192, cdx = e % 192;
    wp[r][cdx] = ldT(Wp, (size_t)(og*32 + r)*CDIM + cdx, isbf);
  }
  __syncthreads();
  int r = tid >> 3, cg = tid & 7;
#pragma unroll 1
  for (int i = 0; i < 24; ++i){
    int dg = cg*24 + i;
    int hh = dg >> 5, d = dg & 31;
    float a = 0.f;
#pragma unroll
    for (int cc = 0; cc < 32; ++cc)
      a += wp[r][hh*32 + cc] * at[hh*1024 + cc*32 + d];
    Mb[(size_t)b*CDIM*CDIM + (size_t)(og*32 + r)*CDIM + dg] = f2b(a);
  }
}

// ---- final: out[b] = M[b] @ v[b]. R4: LDS epilogue for bf16 path.
__global__ __launch_bounds__(256) void k_out(const unsigned short* v, const unsigned short* Mb,
    void* out, const int* flag){
  __shared__ unsigned short Bt[64][200];
  __shared__ unsigned short outb[192][72];
  int tid = threadIdx.x;
  int nt = blockIdx.x, b = blockIdx.y;
  int n0 = nt * 64;
  for (int r = tid; r < 1536; r += 256){
    int k = r >> 3, j8 = (r & 7) * 8;
    bf16x8 vv = *(const bf16x8*)(v + (size_t)(b*CDIM + k)*NPIX + n0 + j8);
#pragma unroll
    for (int i = 0; i < 8; ++i) Bt[j8+i][k] = (unsigned short)vv[i];
  }
  __syncthreads();
  int w = tid >> 6, l = tid & 63, lr = l & 15, lk = l >> 4;
  const unsigned short* A = Mb + (size_t)b*CDIM*CDIM;
  f32x4 acc[3][4] = {};
  for (int kc = 0; kc < 6; ++kc){
    bf16x8 af[3];
#pragma unroll
    for (int g = 0; g < 3; ++g)
      af[g] = *(const bf16x8*)(A + (size_t)(g*64 + w*16 + lr)*CDIM + kc*32 + lk*8);
#pragma unroll
    for (int nf = 0; nf < 4; ++nf){
      bf16x8 bfv = *(const bf16x8*)(&Bt[nf*16 + lr][kc*32 + lk*8]);
#pragma unroll
      for (int g = 0; g < 3; ++g) acc[g][nf] = MF(af[g], bfv, acc[g][nf]);
    }
  }
  int isbf = *flag;
  if (isbf){
#pragma unroll
    for (int g = 0; g < 3; ++g)
#pragma unroll
      for (int nf = 0; nf < 4; ++nf)
#pragma unroll
        for (int r = 0; r < 4; ++r)
          outb[g*64 + w*16 + lk*4 + r][nf*16 + lr] = f2b(acc[g][nf][r]);
    __syncthreads();
    unsigned short* dst = (unsigned short*)out + (size_t)b*CDIM*NPIX;
    for (int e = tid; e < 1536; e += 256){
      int m = e >> 3, p8 = (e & 7) * 8;
      *(bf16x8*)(dst + (size_t)m*NPIX + n0 + p8) = *(const bf16x8*)(&outb[m][p8]);
    }
  } else {
#pragma unroll
    for (int g = 0; g < 3; ++g)
#pragma unroll
      for (int nf = 0; nf < 4; ++nf)
#pragma unroll
        for (int r = 0; r < 4; ++r){
          int m = g*64 + w*16 + lk*4 + r;
          ((float*)out)[(size_t)(b*CDIM + m)*NPIX + n0 + nf*16 + lr] = acc[g][nf][r];
        }
  }
}

extern "C" void kernel_launch(void* const* d_in, const int* in_sizes, int n_in,
                              void* d_out, int out_size, void* d_ws, size_t ws_size,
                              hipStream_t stream){
  const void* x   = d_in[0];
  const void* Wq  = d_in[1];
  const void* Wk  = d_in[2];
  const void* Wv  = d_in[3];
  const void* Wqd = d_in[4];
  const void* Wkd = d_in[5];
  const void* Wvd = d_in[6];
  const void* rsc = d_in[7];
  const void* Wp  = d_in[8];

  char* ws = (char*)d_ws;
  size_t o = 0;
  int* flag             = (int*)(ws + o);            o += 256;
  unsigned short* Wqkv  = (unsigned short*)(ws + o); o += (size_t)576*192*2;
  unsigned short* q0    = (unsigned short*)(ws + o); o += (size_t)NB*CDIM*NPIX*2;
  unsigned short* k0    = (unsigned short*)(ws + o); o += (size_t)NB*CDIM*NPIX*2;
  unsigned short* v0    = (unsigned short*)(ws + o); o += (size_t)NB*CDIM*NPIX*2;
  float* Spart          = (float*)(ws + o);          o += (size_t)384*1024*4;
  float* Nsq            = (float*)(ws + o);          o += (size_t)NB*2*CDIM*4;
  float* attnG          = (float*)(ws + o);          o += (size_t)48*1024*4;
  unsigned short* Mb    = (unsigned short*)(ws + o); o += (size_t)NB*CDIM*CDIM*2;

  k_detect<<<dim3(1), 64, 0, stream>>>((const unsigned short*)x, flag);
  k_prep  <<<dim3(432), 256, 0, stream>>>(Wq, Wk, Wv, Wqkv, flag);
  k_conv1 <<<dim3(256, NB), 256, 0, stream>>>(x, Wqkv, q0, k0, v0, flag);
  k_dw    <<<dim3(3, CDIM, NB), 256, 0, stream>>>(q0, k0, v0, Wqd, Wkd, Wvd, Nsq, flag);
  k_gram  <<<dim3(8, NHEADS, NB), 256, 0, stream>>>(q0, k0, Spart);
  k_attn  <<<dim3(48), 256, 0, stream>>>(Spart, Nsq, rsc, attnG, flag);
  k_mmat  <<<dim3(NB, 6), 256, 0, stream>>>(Wp, attnG, Mb, flag);
  k_out   <<<dim3(256, NB), 256, 0, stream>>>(v0, Mb, d_out, flag);
}